// Round 15
// baseline (68.606 us; speedup 1.0000x reference)
//
#include <hip/hip_runtime.h>
#include <hip/hip_bf16.h>

typedef __attribute__((ext_vector_type(8))) __bf16 bf16x8;
typedef __attribute__((ext_vector_type(4))) float f32x4;
typedef __attribute__((ext_vector_type(8))) unsigned short ushort8;
typedef __attribute__((ext_vector_type(4))) unsigned short ushort4v;

__device__ __forceinline__ unsigned short f2bf(float f) {
  unsigned u = __builtin_bit_cast(unsigned, f);
  u += 0x7FFFu + ((u >> 16) & 1u);   // round-to-nearest-even
  return (unsigned short)(u >> 16);
}

__device__ __forceinline__ void gload_lds16(const void* g, void* l) {
  __builtin_amdgcn_global_load_lds(
      (const __attribute__((address_space(1))) void*)g,
      (__attribute__((address_space(3))) void*)l, 16, 0, 0);
}

__device__ __forceinline__ void barrier_fence() {
  __builtin_amdgcn_s_barrier();
  asm volatile("" ::: "memory");
}

template <int N>
__device__ __forceinline__ void waitvm() {
  if constexpr (N == 0)      asm volatile("s_waitcnt vmcnt(0)" ::: "memory");
  else if constexpr (N == 8) asm volatile("s_waitcnt vmcnt(8)" ::: "memory");
}

// ---- prep: weight conversions only ----
// [0,2048)    : U[4096][512] -> Ut[512][4096] bf16 (transpose)
// [2048,2560) : W[1024][512] -> Wt[512][1024] bf16 (transpose)
// [2560,3584) : V   (2M f32) -> Vb bf16
__global__ __launch_bounds__(256) void prep_kernel(
    const float* __restrict__ U, unsigned short* __restrict__ Ut,
    const float* __restrict__ W, unsigned short* __restrict__ Wt,
    const float* __restrict__ V, unsigned short* __restrict__ Vb) {
  __shared__ float tile[32][33];
  const int b = blockIdx.x;
  const int tid = threadIdx.x;
  if (b < 2560) {
    const float* src;
    unsigned short* dst;
    int rows, cols, bx, by;
    if (b < 2048) {
      src = U; dst = Ut; rows = 4096; cols = 512;
      bx = (b & 15) * 32; by = (b >> 4) * 32;
    } else {
      int bb = b - 2048;
      src = W; dst = Wt; rows = 1024; cols = 512;
      bx = (bb & 15) * 32; by = (bb >> 4) * 32;
    }
    const int tx = tid & 31, ty = tid >> 5;
    for (int i = ty; i < 32; i += 8)
      tile[i][tx] = src[(size_t)(by + i) * cols + bx + tx];
    __syncthreads();
    for (int i = ty; i < 32; i += 8)
      dst[(size_t)(bx + i) * rows + by + tx] = f2bf(tile[tx][i]);
  } else {
    const size_t i = (size_t)(b - 2560) * 256 + tid;  // 8 f32 per thread
    const float4* s4 = reinterpret_cast<const float4*>(V) + 2 * i;
    float4 a = s4[0], c = s4[1];
    ushort8 o;
    o[0] = f2bf(a.x); o[1] = f2bf(a.y); o[2] = f2bf(a.z); o[3] = f2bf(a.w);
    o[4] = f2bf(c.x); o[5] = f2bf(c.y); o[6] = f2bf(c.z); o[7] = f2bf(c.w);
    *(reinterpret_cast<ushort8*>(Vb) + i) = o;
  }
}

// ======== bf16 GEMM core (gemm2): 128x128, counted-vmcnt DEPTH=2 ========
// A,Bt bf16 via global_load_lds.  Caller passes both offset to K-chunk start.
// COLMAP: XCD chunks advance along rows within a column stripe (B-panel reuse).
// EPI 2: outf[idx] = relu(acc + e0[col]); EPI 3: outf[idx] = acc (partial).
template <int FM, int FN, int EPI, int DEPTH, bool COLMAP>
__device__ __forceinline__ void gemm_core(
    const unsigned short* __restrict__ A, const unsigned short* __restrict__ Bt,
    int N, int lda, int kchunk, const float* __restrict__ e0,
    float* __restrict__ outf, int nwg, int bid) {
  constexpr int BM = 32 * FM, BN = 32 * FN, BK = 64;
  constexpr int AI = FM, BI = FN;
  constexpr int ISS = AI + BI;
  __shared__ unsigned short lds[DEPTH][(BM + BN) * BK];

  const int tid = threadIdx.x;
  const int wid = tid >> 6;
  const int lane = tid & 63;
  const int wr = wid >> 1, wc = wid & 1;

  const int swz = (bid & 7) * (nwg >> 3) + (bid >> 3);
  const int nbn = N / BN;
  int brow, bcol;
  if constexpr (COLMAP) {
    const int nbm = nwg / nbn;
    brow = (swz % nbm) * BM;
    bcol = (swz / nbm) * BN;
  } else {
    brow = (swz / nbn) * BM;
    bcol = (swz % nbn) * BN;
  }

  f32x4 zero = {0.f, 0.f, 0.f, 0.f};
  f32x4 acc[FM][FN];
#pragma unroll
  for (int m = 0; m < FM; ++m)
#pragma unroll
    for (int n = 0; n < FN; ++n) acc[m][n] = zero;

  const int lr = lane >> 3;
  const int swzc = ((lane & 7) ^ lr) * 8;
  const unsigned short* Agh = A + (size_t)(brow + wid * (BM / 4) + lr) * lda + swzc;
  const unsigned short* Bgh = Bt + (size_t)(bcol + wid * (BN / 4) + lr) * lda + swzc;

  const int frow = lane & 15;
  const int fhi = lane >> 4;

  const int nsteps = kchunk / BK;

  auto stage = [&](int b, int kofs) {
    unsigned short* AsW = lds[b] + wid * (BM / 4) * 64;
#pragma unroll
    for (int i = 0; i < AI; ++i)
      gload_lds16(Agh + kofs + (size_t)(8 * i) * lda, AsW + i * 512);
    unsigned short* BsW = lds[b] + BM * BK + wid * (BN / 4) * 64;
#pragma unroll
    for (int i = 0; i < BI; ++i)
      gload_lds16(Bgh + kofs + (size_t)(8 * i) * lda, BsW + i * 512);
  };

  auto compute = [&](int cur) {
    const unsigned short* As = lds[cur];
    const unsigned short* Bs = lds[cur] + BM * BK;
#pragma unroll
    for (int ks = 0; ks < 2; ++ks) {
      bf16x8 af[FM], bg[FN];
#pragma unroll
      for (int m = 0; m < FM; ++m) {
        int row = wr * FM * 16 + m * 16 + frow;
        int pc = (ks * 4 + fhi) ^ (row & 7);
        af[m] = *reinterpret_cast<const bf16x8*>(As + row * 64 + pc * 8);
      }
#pragma unroll
      for (int n = 0; n < FN; ++n) {
        int row = wc * FN * 16 + n * 16 + frow;
        int pc = (ks * 4 + fhi) ^ (row & 7);
        bg[n] = *reinterpret_cast<const bf16x8*>(Bs + row * 64 + pc * 8);
      }
#pragma unroll
      for (int m = 0; m < FM; ++m)
#pragma unroll
        for (int n = 0; n < FN; ++n)
          acc[m][n] = __builtin_amdgcn_mfma_f32_16x16x32_bf16(af[m], bg[n],
                                                              acc[m][n], 0, 0, 0);
    }
  };

#pragma unroll
  for (int d = 0; d < DEPTH; ++d) stage(d, d * BK);

  int cur = 0;
  for (int t = 0; t < nsteps; ++t) {
    const int ahead = nsteps - 1 - t;
    if (ahead >= DEPTH - 1)
      waitvm<(DEPTH - 1) * ISS>();
    else
      waitvm<0>();
    barrier_fence();
    compute(cur);
    if (t + 1 < nsteps) {
      asm volatile("s_waitcnt lgkmcnt(0)" ::: "memory");
      barrier_fence();
      if (t + DEPTH < nsteps) stage(cur, (t + DEPTH) * BK);
    }
    cur = (cur + 1 == DEPTH) ? 0 : cur + 1;
  }

#pragma unroll
  for (int m = 0; m < FM; ++m) {
    int gr0 = brow + wr * FM * 16 + m * 16 + fhi * 4;
#pragma unroll
    for (int n = 0; n < FN; ++n) {
      int gc = bcol + wc * FN * 16 + n * 16 + frow;
#pragma unroll
      for (int j = 0; j < 4; ++j) {
        size_t idx = (size_t)(gr0 + j) * N + gc;
        float v = acc[m][n][j];
        if constexpr (EPI == 2) {
          v += e0[gc];
          outf[idx] = v > 0.f ? v : 0.f;
        } else {
          outf[idx] = v;
        }
      }
    }
  }
}

// ======== f32-A GEMM core (gemm01): 128x128, fused cvt, 1 barrier/step ======
// Identical schedule to round 14 (proven).  EPI 3: partial; EPI 0: v + e0[col].
template <int EPI>
__device__ __forceinline__ void gemm_core_f32a(
    const float* __restrict__ A, const unsigned short* __restrict__ Bt,
    int lda, int kchunk, const float* __restrict__ e0,
    float* __restrict__ outf, int nwg, int bid) {
  constexpr int N = 512;
  constexpr int BM = 128, BN = 128, BK = 64;
  __shared__ unsigned short lds[2][(BM + BN) * BK];  // 2 x 32 KB

  const int tid = threadIdx.x;
  const int wid = tid >> 6;
  const int lane = tid & 63;
  const int wr = wid >> 1, wc = wid & 1;

  const int swz = (bid & 7) * (nwg >> 3) + (bid >> 3);
  const int nbn = N / BN;        // 4
  const int brow = (swz / nbn) * BM;
  const int bcol = (swz % nbn) * BN;

  f32x4 zero = {0.f, 0.f, 0.f, 0.f};
  f32x4 acc[4][4];
#pragma unroll
  for (int m = 0; m < 4; ++m)
#pragma unroll
    for (int n = 0; n < 4; ++n) acc[m][n] = zero;

  const int lr = lane >> 3;      // 0..7
  const int lc = lane & 7;       // phys 16B chunk
  const int swzc = (lc ^ lr) * 8;
  const float* Agf = A + (size_t)(brow + wid * 32 + lr) * lda + swzc;
  const unsigned short* Bgh = Bt + (size_t)(bcol + wid * 32 + lr) * lda + swzc;

  const int frow = lane & 15;
  const int fhi = lane >> 4;

  const int nsteps = kchunk / BK;  // >= 2

  float4 areg[4][2];
  auto aload = [&](int kofs) {
#pragma unroll
    for (int i = 0; i < 4; ++i) {
      const float* s = Agf + kofs + (size_t)(8 * i) * lda;
      areg[i][0] = *reinterpret_cast<const float4*>(s);
      areg[i][1] = *reinterpret_cast<const float4*>(s + 4);
    }
  };
  auto awrite = [&](int b) {
    unsigned short* AsW = lds[b] + wid * 2048 + lane * 8;
#pragma unroll
    for (int i = 0; i < 4; ++i) {
      float4 x = areg[i][0], y = areg[i][1];
      ushort8 o;
      o[0] = f2bf(x.x); o[1] = f2bf(x.y); o[2] = f2bf(x.z); o[3] = f2bf(x.w);
      o[4] = f2bf(y.x); o[5] = f2bf(y.y); o[6] = f2bf(y.z); o[7] = f2bf(y.w);
      *reinterpret_cast<ushort8*>(AsW + i * 512) = o;
    }
  };
  auto bload = [&](int b, int kofs) {
    unsigned short* BsW = lds[b] + BM * BK + wid * 2048;
#pragma unroll
    for (int i = 0; i < 4; ++i)
      gload_lds16(Bgh + kofs + (size_t)(8 * i) * lda, BsW + i * 512);
  };

  auto compute = [&](int cur) {
    const unsigned short* As = lds[cur];
    const unsigned short* Bs = lds[cur] + BM * BK;
#pragma unroll
    for (int ks = 0; ks < 2; ++ks) {
      bf16x8 af[4], bg[4];
#pragma unroll
      for (int m = 0; m < 4; ++m) {
        int row = wr * 64 + m * 16 + frow;
        int pc = (ks * 4 + fhi) ^ (row & 7);
        af[m] = *reinterpret_cast<const bf16x8*>(As + row * 64 + pc * 8);
      }
#pragma unroll
      for (int n = 0; n < 4; ++n) {
        int row = wc * 64 + n * 16 + frow;
        int pc = (ks * 4 + fhi) ^ (row & 7);
        bg[n] = *reinterpret_cast<const bf16x8*>(Bs + row * 64 + pc * 8);
      }
#pragma unroll
      for (int m = 0; m < 4; ++m)
#pragma unroll
        for (int n = 0; n < 4; ++n)
          acc[m][n] = __builtin_amdgcn_mfma_f32_16x16x32_bf16(af[m], bg[n],
                                                              acc[m][n], 0, 0, 0);
    }
  };

  // prologue
  aload(0);
  bload(0, 0);
  waitvm<0>();
  awrite(0);
  aload(BK);
  asm volatile("s_waitcnt lgkmcnt(0)" ::: "memory");
  barrier_fence();

  for (int t = 0; t < nsteps; ++t) {
    const int cur = t & 1;
    if (t + 1 < nsteps) bload(cur ^ 1, (t + 1) * BK);
    compute(cur);
    if (t + 1 < nsteps) {
      waitvm<0>();
      awrite(cur ^ 1);
      if (t + 2 < nsteps) aload((t + 2) * BK);
      asm volatile("s_waitcnt lgkmcnt(0)" ::: "memory");
      barrier_fence();
    }
  }

  // epilogue
#pragma unroll
  for (int m = 0; m < 4; ++m) {
    int gr0 = brow + wr * 64 + m * 16 + fhi * 4;
#pragma unroll
    for (int n = 0; n < 4; ++n) {
      int gc = bcol + wc * 64 + n * 16 + frow;
#pragma unroll
      for (int j = 0; j < 4; ++j) {
        float v = acc[m][n][j];
        if constexpr (EPI == 0) v += e0[gc];
        outf[(size_t)(gr0 + j) * N + gc] = v;
      }
    }
  }
}

// ---- merged GEMMs, f32 A fused-cvt, 128x128 tiles ----
// blocks [0,256)   : inputs@U split-4 (lda 4096, kchunk 1024) -> p1 partials
// blocks [256,320) : context@W UNSPLIT (lda 1024, kchunk 1024) -> sbuf = +S
__global__ __launch_bounds__(256) void gemm01_kernel(
    const float* __restrict__ inp, const unsigned short* __restrict__ Ut,
    const float* __restrict__ ctx, const unsigned short* __restrict__ Wt,
    const float* __restrict__ S, float* __restrict__ sbuf,
    float* __restrict__ p1) {
  const int bid = (int)blockIdx.x;
  constexpr size_t MN = (size_t)2048 * 512;
  if (bid < 256) {
    const int split = bid >> 6;          // 4 splits x 64 positions
    gemm_core_f32a<3>(inp + (size_t)split * 1024, Ut + (size_t)split * 1024,
                      4096, 1024, nullptr, p1 + split * MN, 64, bid & 63);
  } else {
    gemm_core_f32a<0>(ctx, Wt, 1024, 1024, S, sbuf, 64, bid - 256);
  }
}

// ---- final GEMM: out = relu(xus @ V^T + bias), 128x128, COLMAP ----
__global__ __launch_bounds__(256) void gemm2_kernel(
    const unsigned short* __restrict__ xus, const unsigned short* __restrict__ Vb,
    const float* __restrict__ bias, float* __restrict__ out) {
  gemm_core<4, 4, 2, 2, true>(xus, Vb, 4096, 512, 512, bias, out, 512,
                              (int)blockIdx.x);
}

// ---- fused split-K reduce: xus = bf16((sum p1) * s) ----
__global__ void reduce_mul_kernel(const float* __restrict__ p1,  // [4][MN]
                                  const float* __restrict__ sbuf,  // [MN]
                                  unsigned short* __restrict__ xus, int MN) {
  int i = blockIdx.x * blockDim.x + threadIdx.x;
  size_t base = (size_t)i * 4;
  if (base >= (size_t)MN) return;
  float4 a = *reinterpret_cast<const float4*>(p1 + base);
  float4 b = *reinterpret_cast<const float4*>(p1 + (size_t)MN + base);
  float4 c = *reinterpret_cast<const float4*>(p1 + 2 * (size_t)MN + base);
  float4 d = *reinterpret_cast<const float4*>(p1 + 3 * (size_t)MN + base);
  float4 s = *reinterpret_cast<const float4*>(sbuf + base);
  float4 xu;
  xu.x = (a.x + b.x) + (c.x + d.x);
  xu.y = (a.y + b.y) + (c.y + d.y);
  xu.z = (a.z + b.z) + (c.z + d.z);
  xu.w = (a.w + b.w) + (c.w + d.w);
  ushort4v o;
  o[0] = f2bf(xu.x * s.x);
  o[1] = f2bf(xu.y * s.y);
  o[2] = f2bf(xu.z * s.z);
  o[3] = f2bf(xu.w * s.w);
  *reinterpret_cast<ushort4v*>(xus + base) = o;
}

extern "C" void kernel_launch(void* const* d_in, const int* in_sizes, int n_in,
                              void* d_out, int out_size, void* d_ws, size_t ws_size,
                              hipStream_t stream) {
  constexpr int Bm = 2048, Nn = 4096, Cc = 1024, UU = 4096, RR = 512;
  const float* inputs  = (const float*)d_in[0];
  const float* context = (const float*)d_in[1];
  const float* U       = (const float*)d_in[2];
  const float* S       = (const float*)d_in[3];
  const float* V       = (const float*)d_in[4];
  const float* W       = (const float*)d_in[5];
  const float* bias    = (const float*)d_in[6];
  float* out = (float*)d_out;

  char* p = (char*)d_ws;
  unsigned short* Ut   = (unsigned short*)p; p += (size_t)RR * Nn * 2;      //  4 MB
  unsigned short* Wt   = (unsigned short*)p; p += (size_t)RR * Cc * 2;      //  1 MB
  unsigned short* Vb   = (unsigned short*)p; p += (size_t)UU * RR * 2;      //  4 MB
  float*          sbuf = (float*)p;          p += (size_t)Bm * RR * 4;      //  4 MB
  float*          p1   = (float*)p;          p += (size_t)4 * Bm * RR * 4;  // 16 MB
  unsigned short* xus  = (unsigned short*)p; p += (size_t)Bm * RR * 2;      //  2 MB

  // 1) prep: U^T, W^T, V -> bf16
  prep_kernel<<<3584, 256, 0, stream>>>(U, Ut, W, Wt, V, Vb);

  // 2) merged: p1[4] = inputs@U split-4 partials; sbuf = S + context@W (unsplit)
  gemm01_kernel<<<320, 256, 0, stream>>>(inputs, Ut, context, Wt, S, sbuf, p1);

  // 3) xus = bf16((sum p1) * sbuf)
  reduce_mul_kernel<<<Bm * RR / 4 / 256, 256, 0, stream>>>(p1, sbuf, xus, Bm * RR);

  // 4) out = relu(xus @ V^T + bias)   (128x128 tiles, col-chunked XCD map)
  gemm2_kernel<<<512, 256, 0, stream>>>(xus, Vb, bias, out);
}

// Round 16
// 62.039 us; speedup vs baseline: 1.1059x; 1.1059x over previous
//
#include <hip/hip_runtime.h>
#include <hip/hip_bf16.h>

typedef __attribute__((ext_vector_type(8))) __bf16 bf16x8;
typedef __attribute__((ext_vector_type(4))) float f32x4;
typedef __attribute__((ext_vector_type(8))) unsigned short ushort8;
typedef __attribute__((ext_vector_type(4))) unsigned short ushort4v;

__device__ __forceinline__ unsigned short f2bf(float f) {
  unsigned u = __builtin_bit_cast(unsigned, f);
  u += 0x7FFFu + ((u >> 16) & 1u);   // round-to-nearest-even
  return (unsigned short)(u >> 16);
}

__device__ __forceinline__ void gload_lds16(const void* g, void* l) {
  __builtin_amdgcn_global_load_lds(
      (const __attribute__((address_space(1))) void*)g,
      (__attribute__((address_space(3))) void*)l, 16, 0, 0);
}

__device__ __forceinline__ void barrier_fence() {
  __builtin_amdgcn_s_barrier();
  asm volatile("" ::: "memory");
}

template <int N>
__device__ __forceinline__ void waitvm() {
  if constexpr (N == 0)      asm volatile("s_waitcnt vmcnt(0)" ::: "memory");
  else if constexpr (N == 8) asm volatile("s_waitcnt vmcnt(8)" ::: "memory");
}

// ---- prep: weight conversions only ----
// [0,2048)    : U[4096][512] -> Ut[512][4096] bf16 (transpose)
// [2048,2560) : W[1024][512] -> Wt[512][1024] bf16 (transpose)
// [2560,3584) : V   (2M f32) -> Vb bf16
__global__ __launch_bounds__(256) void prep_kernel(
    const float* __restrict__ U, unsigned short* __restrict__ Ut,
    const float* __restrict__ W, unsigned short* __restrict__ Wt,
    const float* __restrict__ V, unsigned short* __restrict__ Vb) {
  __shared__ float tile[32][33];
  const int b = blockIdx.x;
  const int tid = threadIdx.x;
  if (b < 2560) {
    const float* src;
    unsigned short* dst;
    int rows, cols, bx, by;
    if (b < 2048) {
      src = U; dst = Ut; rows = 4096; cols = 512;
      bx = (b & 15) * 32; by = (b >> 4) * 32;
    } else {
      int bb = b - 2048;
      src = W; dst = Wt; rows = 1024; cols = 512;
      bx = (bb & 15) * 32; by = (bb >> 4) * 32;
    }
    const int tx = tid & 31, ty = tid >> 5;
    for (int i = ty; i < 32; i += 8)
      tile[i][tx] = src[(size_t)(by + i) * cols + bx + tx];
    __syncthreads();
    for (int i = ty; i < 32; i += 8)
      dst[(size_t)(bx + i) * rows + by + tx] = f2bf(tile[tx][i]);
  } else {
    const size_t i = (size_t)(b - 2560) * 256 + tid;  // 8 f32 per thread
    const float4* s4 = reinterpret_cast<const float4*>(V) + 2 * i;
    float4 a = s4[0], c = s4[1];
    ushort8 o;
    o[0] = f2bf(a.x); o[1] = f2bf(a.y); o[2] = f2bf(a.z); o[3] = f2bf(a.w);
    o[4] = f2bf(c.x); o[5] = f2bf(c.y); o[6] = f2bf(c.z); o[7] = f2bf(c.w);
    *(reinterpret_cast<ushort8*>(Vb) + i) = o;
  }
}

// ======== bf16 GEMM core (gemm2): 128x128, counted-vmcnt DEPTH=2 ========
// A,Bt bf16 via global_load_lds.  COLMAP: XCD chunks advance along rows
// within a column stripe (B-panel reuse per XCD-L2).
// EPI 2: outf[idx] = relu(acc + e0[col]).
template <int FM, int FN, int EPI, int DEPTH, bool COLMAP>
__device__ __forceinline__ void gemm_core(
    const unsigned short* __restrict__ A, const unsigned short* __restrict__ Bt,
    int N, int lda, int kchunk, const float* __restrict__ e0,
    float* __restrict__ outf, int nwg, int bid) {
  constexpr int BM = 32 * FM, BN = 32 * FN, BK = 64;
  constexpr int AI = FM, BI = FN;
  constexpr int ISS = AI + BI;
  __shared__ unsigned short lds[DEPTH][(BM + BN) * BK];

  const int tid = threadIdx.x;
  const int wid = tid >> 6;
  const int lane = tid & 63;
  const int wr = wid >> 1, wc = wid & 1;

  const int swz = (bid & 7) * (nwg >> 3) + (bid >> 3);
  const int nbn = N / BN;
  int brow, bcol;
  if constexpr (COLMAP) {
    const int nbm = nwg / nbn;
    brow = (swz % nbm) * BM;
    bcol = (swz / nbm) * BN;
  } else {
    brow = (swz / nbn) * BM;
    bcol = (swz % nbn) * BN;
  }

  f32x4 zero = {0.f, 0.f, 0.f, 0.f};
  f32x4 acc[FM][FN];
#pragma unroll
  for (int m = 0; m < FM; ++m)
#pragma unroll
    for (int n = 0; n < FN; ++n) acc[m][n] = zero;

  const int lr = lane >> 3;
  const int swzc = ((lane & 7) ^ lr) * 8;
  const unsigned short* Agh = A + (size_t)(brow + wid * (BM / 4) + lr) * lda + swzc;
  const unsigned short* Bgh = Bt + (size_t)(bcol + wid * (BN / 4) + lr) * lda + swzc;

  const int frow = lane & 15;
  const int fhi = lane >> 4;

  const int nsteps = kchunk / BK;

  auto stage = [&](int b, int kofs) {
    unsigned short* AsW = lds[b] + wid * (BM / 4) * 64;
#pragma unroll
    for (int i = 0; i < AI; ++i)
      gload_lds16(Agh + kofs + (size_t)(8 * i) * lda, AsW + i * 512);
    unsigned short* BsW = lds[b] + BM * BK + wid * (BN / 4) * 64;
#pragma unroll
    for (int i = 0; i < BI; ++i)
      gload_lds16(Bgh + kofs + (size_t)(8 * i) * lda, BsW + i * 512);
  };

  auto compute = [&](int cur) {
    const unsigned short* As = lds[cur];
    const unsigned short* Bs = lds[cur] + BM * BK;
#pragma unroll
    for (int ks = 0; ks < 2; ++ks) {
      bf16x8 af[FM], bg[FN];
#pragma unroll
      for (int m = 0; m < FM; ++m) {
        int row = wr * FM * 16 + m * 16 + frow;
        int pc = (ks * 4 + fhi) ^ (row & 7);
        af[m] = *reinterpret_cast<const bf16x8*>(As + row * 64 + pc * 8);
      }
#pragma unroll
      for (int n = 0; n < FN; ++n) {
        int row = wc * FN * 16 + n * 16 + frow;
        int pc = (ks * 4 + fhi) ^ (row & 7);
        bg[n] = *reinterpret_cast<const bf16x8*>(Bs + row * 64 + pc * 8);
      }
#pragma unroll
      for (int m = 0; m < FM; ++m)
#pragma unroll
        for (int n = 0; n < FN; ++n)
          acc[m][n] = __builtin_amdgcn_mfma_f32_16x16x32_bf16(af[m], bg[n],
                                                              acc[m][n], 0, 0, 0);
    }
  };

#pragma unroll
  for (int d = 0; d < DEPTH; ++d) stage(d, d * BK);

  int cur = 0;
  for (int t = 0; t < nsteps; ++t) {
    const int ahead = nsteps - 1 - t;
    if (ahead >= DEPTH - 1)
      waitvm<(DEPTH - 1) * ISS>();
    else
      waitvm<0>();
    barrier_fence();
    compute(cur);
    if (t + 1 < nsteps) {
      asm volatile("s_waitcnt lgkmcnt(0)" ::: "memory");
      barrier_fence();
      if (t + DEPTH < nsteps) stage(cur, (t + DEPTH) * BK);
    }
    cur = (cur + 1 == DEPTH) ? 0 : cur + 1;
  }

#pragma unroll
  for (int m = 0; m < FM; ++m) {
    int gr0 = brow + wr * FM * 16 + m * 16 + fhi * 4;
#pragma unroll
    for (int n = 0; n < FN; ++n) {
      int gc = bcol + wc * FN * 16 + n * 16 + frow;
#pragma unroll
      for (int j = 0; j < 4; ++j) {
        size_t idx = (size_t)(gr0 + j) * N + gc;
        float v = acc[m][n][j];
        if constexpr (EPI == 2) {
          v += e0[gc];
          outf[idx] = v > 0.f ? v : 0.f;
        } else {
          outf[idx] = v;
        }
      }
    }
  }
}

// ======== f32-A GEMM core (gemm01): 128x128, fused cvt, 1 barrier/step ======
// NON-TEMPLATE, single call site => single 64 KB LDS allocation (round-15's
// template<EPI> version instantiated twice -> 128 KB LDS -> occupancy halved).
// Epilogue: outf[idx] = acc (+ e0[col] if e0 != nullptr; block-uniform branch).
__device__ __forceinline__ void gemm_core_f32a(
    const float* __restrict__ A, const unsigned short* __restrict__ Bt,
    int lda, const float* __restrict__ e0,
    float* __restrict__ outf, int nwg, int bid) {
  constexpr int N = 512;
  constexpr int BM = 128, BN = 128, BK = 64;
  constexpr int kchunk = 1024;     // both sub-problems use kchunk=1024
  __shared__ unsigned short lds[2][(BM + BN) * BK];  // 2 x 32 KB

  const int tid = threadIdx.x;
  const int wid = tid >> 6;
  const int lane = tid & 63;
  const int wr = wid >> 1, wc = wid & 1;

  const int swz = (bid & 7) * (nwg >> 3) + (bid >> 3);
  const int nbn = N / BN;        // 4
  const int brow = (swz / nbn) * BM;
  const int bcol = (swz % nbn) * BN;

  f32x4 zero = {0.f, 0.f, 0.f, 0.f};
  f32x4 acc[4][4];
#pragma unroll
  for (int m = 0; m < 4; ++m)
#pragma unroll
    for (int n = 0; n < 4; ++n) acc[m][n] = zero;

  const int lr = lane >> 3;      // 0..7
  const int lc = lane & 7;       // phys 16B chunk
  const int swzc = (lc ^ lr) * 8;
  const float* Agf = A + (size_t)(brow + wid * 32 + lr) * lda + swzc;
  const unsigned short* Bgh = Bt + (size_t)(bcol + wid * 32 + lr) * lda + swzc;

  const int frow = lane & 15;
  const int fhi = lane >> 4;

  const int nsteps = kchunk / BK;  // 16

  float4 areg[4][2];
  auto aload = [&](int kofs) {
#pragma unroll
    for (int i = 0; i < 4; ++i) {
      const float* s = Agf + kofs + (size_t)(8 * i) * lda;
      areg[i][0] = *reinterpret_cast<const float4*>(s);
      areg[i][1] = *reinterpret_cast<const float4*>(s + 4);
    }
  };
  auto awrite = [&](int b) {
    unsigned short* AsW = lds[b] + wid * 2048 + lane * 8;
#pragma unroll
    for (int i = 0; i < 4; ++i) {
      float4 x = areg[i][0], y = areg[i][1];
      ushort8 o;
      o[0] = f2bf(x.x); o[1] = f2bf(x.y); o[2] = f2bf(x.z); o[3] = f2bf(x.w);
      o[4] = f2bf(y.x); o[5] = f2bf(y.y); o[6] = f2bf(y.z); o[7] = f2bf(y.w);
      *reinterpret_cast<ushort8*>(AsW + i * 512) = o;
    }
  };
  auto bload = [&](int b, int kofs) {
    unsigned short* BsW = lds[b] + BM * BK + wid * 2048;
#pragma unroll
    for (int i = 0; i < 4; ++i)
      gload_lds16(Bgh + kofs + (size_t)(8 * i) * lda, BsW + i * 512);
  };

  auto compute = [&](int cur) {
    const unsigned short* As = lds[cur];
    const unsigned short* Bs = lds[cur] + BM * BK;
#pragma unroll
    for (int ks = 0; ks < 2; ++ks) {
      bf16x8 af[4], bg[4];
#pragma unroll
      for (int m = 0; m < 4; ++m) {
        int row = wr * 64 + m * 16 + frow;
        int pc = (ks * 4 + fhi) ^ (row & 7);
        af[m] = *reinterpret_cast<const bf16x8*>(As + row * 64 + pc * 8);
      }
#pragma unroll
      for (int n = 0; n < 4; ++n) {
        int row = wc * 64 + n * 16 + frow;
        int pc = (ks * 4 + fhi) ^ (row & 7);
        bg[n] = *reinterpret_cast<const bf16x8*>(Bs + row * 64 + pc * 8);
      }
#pragma unroll
      for (int m = 0; m < 4; ++m)
#pragma unroll
        for (int n = 0; n < 4; ++n)
          acc[m][n] = __builtin_amdgcn_mfma_f32_16x16x32_bf16(af[m], bg[n],
                                                              acc[m][n], 0, 0, 0);
    }
  };

  // prologue
  aload(0);
  bload(0, 0);
  waitvm<0>();
  awrite(0);
  aload(BK);
  asm volatile("s_waitcnt lgkmcnt(0)" ::: "memory");
  barrier_fence();

  for (int t = 0; t < nsteps; ++t) {
    const int cur = t & 1;
    if (t + 1 < nsteps) bload(cur ^ 1, (t + 1) * BK);
    compute(cur);
    if (t + 1 < nsteps) {
      waitvm<0>();     // my A(t+1) regs + my B(t+1) portion landed
      awrite(cur ^ 1);
      if (t + 2 < nsteps) aload((t + 2) * BK);
      asm volatile("s_waitcnt lgkmcnt(0)" ::: "memory");
      barrier_fence();
    }
  }

  // epilogue (e0: block-uniform branch)
#pragma unroll
  for (int m = 0; m < 4; ++m) {
    int gr0 = brow + wr * 64 + m * 16 + fhi * 4;
#pragma unroll
    for (int n = 0; n < 4; ++n) {
      int gc = bcol + wc * 64 + n * 16 + frow;
#pragma unroll
      for (int j = 0; j < 4; ++j) {
        float v = acc[m][n][j];
        if (e0) v += e0[gc];
        outf[(size_t)(gr0 + j) * N + gc] = v;
      }
    }
  }
}

// ---- merged GEMMs, f32 A fused-cvt, 128x128 tiles, ONE call site ----
// blocks [0,256)   : inputs@U split-4 (lda 4096, kchunk 1024) -> p1 partials
// blocks [256,320) : context@W UNSPLIT (lda 1024, kchunk 1024) -> sbuf = +S
__global__ __launch_bounds__(256) void gemm01_kernel(
    const float* __restrict__ inp, const unsigned short* __restrict__ Ut,
    const float* __restrict__ ctx, const unsigned short* __restrict__ Wt,
    const float* __restrict__ S, float* __restrict__ sbuf,
    float* __restrict__ p1) {
  const int bid = (int)blockIdx.x;
  constexpr size_t MN = (size_t)2048 * 512;
  const float* A;
  const unsigned short* Bt;
  int lda, nwg, lbid;
  const float* e0;
  float* outp;
  if (bid < 256) {
    const int split = bid >> 6;          // 4 splits x 64 positions
    A = inp + (size_t)split * 1024;
    Bt = Ut + (size_t)split * 1024;
    lda = 4096; e0 = nullptr; outp = p1 + split * MN; nwg = 64; lbid = bid & 63;
  } else {
    A = ctx; Bt = Wt; lda = 1024; e0 = S; outp = sbuf; nwg = 64; lbid = bid - 256;
  }
  gemm_core_f32a(A, Bt, lda, e0, outp, nwg, lbid);
}

// ---- final GEMM: out = relu(xus @ V^T + bias), 128x128, COLMAP ----
__global__ __launch_bounds__(256) void gemm2_kernel(
    const unsigned short* __restrict__ xus, const unsigned short* __restrict__ Vb,
    const float* __restrict__ bias, float* __restrict__ out) {
  gemm_core<4, 4, 2, 2, true>(xus, Vb, 4096, 512, 512, bias, out, 512,
                              (int)blockIdx.x);
}

// ---- fused split-K reduce: xus = bf16((sum p1) * s) ----
__global__ void reduce_mul_kernel(const float* __restrict__ p1,  // [4][MN]
                                  const float* __restrict__ sbuf,  // [MN]
                                  unsigned short* __restrict__ xus, int MN) {
  int i = blockIdx.x * blockDim.x + threadIdx.x;
  size_t base = (size_t)i * 4;
  if (base >= (size_t)MN) return;
  float4 a = *reinterpret_cast<const float4*>(p1 + base);
  float4 b = *reinterpret_cast<const float4*>(p1 + (size_t)MN + base);
  float4 c = *reinterpret_cast<const float4*>(p1 + 2 * (size_t)MN + base);
  float4 d = *reinterpret_cast<const float4*>(p1 + 3 * (size_t)MN + base);
  float4 s = *reinterpret_cast<const float4*>(sbuf + base);
  float4 xu;
  xu.x = (a.x + b.x) + (c.x + d.x);
  xu.y = (a.y + b.y) + (c.y + d.y);
  xu.z = (a.z + b.z) + (c.z + d.z);
  xu.w = (a.w + b.w) + (c.w + d.w);
  ushort4v o;
  o[0] = f2bf(xu.x * s.x);
  o[1] = f2bf(xu.y * s.y);
  o[2] = f2bf(xu.z * s.z);
  o[3] = f2bf(xu.w * s.w);
  *reinterpret_cast<ushort4v*>(xus + base) = o;
}

extern "C" void kernel_launch(void* const* d_in, const int* in_sizes, int n_in,
                              void* d_out, int out_size, void* d_ws, size_t ws_size,
                              hipStream_t stream) {
  constexpr int Bm = 2048, Nn = 4096, Cc = 1024, UU = 4096, RR = 512;
  const float* inputs  = (const float*)d_in[0];
  const float* context = (const float*)d_in[1];
  const float* U       = (const float*)d_in[2];
  const float* S       = (const float*)d_in[3];
  const float* V       = (const float*)d_in[4];
  const float* W       = (const float*)d_in[5];
  const float* bias    = (const float*)d_in[6];
  float* out = (float*)d_out;

  char* p = (char*)d_ws;
  unsigned short* Ut   = (unsigned short*)p; p += (size_t)RR * Nn * 2;      //  4 MB
  unsigned short* Wt   = (unsigned short*)p; p += (size_t)RR * Cc * 2;      //  1 MB
  unsigned short* Vb   = (unsigned short*)p; p += (size_t)UU * RR * 2;      //  4 MB
  float*          sbuf = (float*)p;          p += (size_t)Bm * RR * 4;      //  4 MB
  float*          p1   = (float*)p;          p += (size_t)4 * Bm * RR * 4;  // 16 MB
  unsigned short* xus  = (unsigned short*)p; p += (size_t)Bm * RR * 2;      //  2 MB

  // 1) prep: U^T, W^T, V -> bf16
  prep_kernel<<<3584, 256, 0, stream>>>(U, Ut, W, Wt, V, Vb);

  // 2) merged: p1[4] = inputs@U split-4 partials; sbuf = S + context@W (unsplit)
  gemm01_kernel<<<320, 256, 0, stream>>>(inputs, Ut, context, Wt, S, sbuf, p1);

  // 3) xus = bf16((sum p1) * sbuf)
  reduce_mul_kernel<<<Bm * RR / 4 / 256, 256, 0, stream>>>(p1, sbuf, xus, Bm * RR);

  // 4) out = relu(xus @ V^T + bias)   (128x128 tiles, col-chunked XCD map)
  gemm2_kernel<<<512, 256, 0, stream>>>(xus, Vb, bias, out);
}

// Round 17
// 60.451 us; speedup vs baseline: 1.1349x; 1.0263x over previous
//
#include <hip/hip_runtime.h>
#include <hip/hip_bf16.h>

typedef __attribute__((ext_vector_type(8))) __bf16 bf16x8;
typedef __attribute__((ext_vector_type(4))) float f32x4;
typedef __attribute__((ext_vector_type(8))) unsigned short ushort8;
typedef __attribute__((ext_vector_type(4))) unsigned short ushort4v;

__device__ __forceinline__ unsigned short f2bf(float f) {
  unsigned u = __builtin_bit_cast(unsigned, f);
  u += 0x7FFFu + ((u >> 16) & 1u);   // round-to-nearest-even
  return (unsigned short)(u >> 16);
}

__device__ __forceinline__ void gload_lds16(const void* g, void* l) {
  __builtin_amdgcn_global_load_lds(
      (const __attribute__((address_space(1))) void*)g,
      (__attribute__((address_space(3))) void*)l, 16, 0, 0);
}

__device__ __forceinline__ void barrier_fence() {
  __builtin_amdgcn_s_barrier();
  asm volatile("" ::: "memory");
}

template <int N>
__device__ __forceinline__ void waitvm() {
  if constexpr (N == 0)      asm volatile("s_waitcnt vmcnt(0)" ::: "memory");
  else if constexpr (N == 8) asm volatile("s_waitcnt vmcnt(8)" ::: "memory");
}

// ---- prep: weight conversions only ----
// [0,2048)    : U[4096][512] -> Ut[512][4096] bf16 (transpose)
// [2048,2560) : W[1024][512] -> Wt[512][1024] bf16 (transpose)
// [2560,3584) : V   (2M f32) -> Vb bf16
__global__ __launch_bounds__(256) void prep_kernel(
    const float* __restrict__ U, unsigned short* __restrict__ Ut,
    const float* __restrict__ W, unsigned short* __restrict__ Wt,
    const float* __restrict__ V, unsigned short* __restrict__ Vb) {
  __shared__ float tile[32][33];
  const int b = blockIdx.x;
  const int tid = threadIdx.x;
  if (b < 2560) {
    const float* src;
    unsigned short* dst;
    int rows, cols, bx, by;
    if (b < 2048) {
      src = U; dst = Ut; rows = 4096; cols = 512;
      bx = (b & 15) * 32; by = (b >> 4) * 32;
    } else {
      int bb = b - 2048;
      src = W; dst = Wt; rows = 1024; cols = 512;
      bx = (bb & 15) * 32; by = (bb >> 4) * 32;
    }
    const int tx = tid & 31, ty = tid >> 5;
    for (int i = ty; i < 32; i += 8)
      tile[i][tx] = src[(size_t)(by + i) * cols + bx + tx];
    __syncthreads();
    for (int i = ty; i < 32; i += 8)
      dst[(size_t)(bx + i) * rows + by + tx] = f2bf(tile[tx][i]);
  } else {
    const size_t i = (size_t)(b - 2560) * 256 + tid;  // 8 f32 per thread
    const float4* s4 = reinterpret_cast<const float4*>(V) + 2 * i;
    float4 a = s4[0], c = s4[1];
    ushort8 o;
    o[0] = f2bf(a.x); o[1] = f2bf(a.y); o[2] = f2bf(a.z); o[3] = f2bf(a.w);
    o[4] = f2bf(c.x); o[5] = f2bf(c.y); o[6] = f2bf(c.z); o[7] = f2bf(c.w);
    *(reinterpret_cast<ushort8*>(Vb) + i) = o;
  }
}

// ======== bf16 GEMM core (gemm2): 128x128, counted-vmcnt DEPTH=2 ========
// A,Bt bf16 via global_load_lds.  COLMAP: XCD chunks advance along rows
// within a column stripe (B-panel reuse per XCD-L2).
// EPI 2: outf[idx] = relu(acc + e0[col]).
template <int FM, int FN, int EPI, int DEPTH, bool COLMAP>
__device__ __forceinline__ void gemm_core(
    const unsigned short* __restrict__ A, const unsigned short* __restrict__ Bt,
    int N, int lda, int kchunk, const float* __restrict__ e0,
    float* __restrict__ outf, int nwg, int bid) {
  constexpr int BM = 32 * FM, BN = 32 * FN, BK = 64;
  constexpr int AI = FM, BI = FN;
  constexpr int ISS = AI + BI;
  __shared__ unsigned short lds[DEPTH][(BM + BN) * BK];

  const int tid = threadIdx.x;
  const int wid = tid >> 6;
  const int lane = tid & 63;
  const int wr = wid >> 1, wc = wid & 1;

  const int swz = (bid & 7) * (nwg >> 3) + (bid >> 3);
  const int nbn = N / BN;
  int brow, bcol;
  if constexpr (COLMAP) {
    const int nbm = nwg / nbn;
    brow = (swz % nbm) * BM;
    bcol = (swz / nbm) * BN;
  } else {
    brow = (swz / nbn) * BM;
    bcol = (swz % nbn) * BN;
  }

  f32x4 zero = {0.f, 0.f, 0.f, 0.f};
  f32x4 acc[FM][FN];
#pragma unroll
  for (int m = 0; m < FM; ++m)
#pragma unroll
    for (int n = 0; n < FN; ++n) acc[m][n] = zero;

  const int lr = lane >> 3;
  const int swzc = ((lane & 7) ^ lr) * 8;
  const unsigned short* Agh = A + (size_t)(brow + wid * (BM / 4) + lr) * lda + swzc;
  const unsigned short* Bgh = Bt + (size_t)(bcol + wid * (BN / 4) + lr) * lda + swzc;

  const int frow = lane & 15;
  const int fhi = lane >> 4;

  const int nsteps = kchunk / BK;

  auto stage = [&](int b, int kofs) {
    unsigned short* AsW = lds[b] + wid * (BM / 4) * 64;
#pragma unroll
    for (int i = 0; i < AI; ++i)
      gload_lds16(Agh + kofs + (size_t)(8 * i) * lda, AsW + i * 512);
    unsigned short* BsW = lds[b] + BM * BK + wid * (BN / 4) * 64;
#pragma unroll
    for (int i = 0; i < BI; ++i)
      gload_lds16(Bgh + kofs + (size_t)(8 * i) * lda, BsW + i * 512);
  };

  auto compute = [&](int cur) {
    const unsigned short* As = lds[cur];
    const unsigned short* Bs = lds[cur] + BM * BK;
#pragma unroll
    for (int ks = 0; ks < 2; ++ks) {
      bf16x8 af[FM], bg[FN];
#pragma unroll
      for (int m = 0; m < FM; ++m) {
        int row = wr * FM * 16 + m * 16 + frow;
        int pc = (ks * 4 + fhi) ^ (row & 7);
        af[m] = *reinterpret_cast<const bf16x8*>(As + row * 64 + pc * 8);
      }
#pragma unroll
      for (int n = 0; n < FN; ++n) {
        int row = wc * FN * 16 + n * 16 + frow;
        int pc = (ks * 4 + fhi) ^ (row & 7);
        bg[n] = *reinterpret_cast<const bf16x8*>(Bs + row * 64 + pc * 8);
      }
#pragma unroll
      for (int m = 0; m < FM; ++m)
#pragma unroll
        for (int n = 0; n < FN; ++n)
          acc[m][n] = __builtin_amdgcn_mfma_f32_16x16x32_bf16(af[m], bg[n],
                                                              acc[m][n], 0, 0, 0);
    }
  };

#pragma unroll
  for (int d = 0; d < DEPTH; ++d) stage(d, d * BK);

  int cur = 0;
  for (int t = 0; t < nsteps; ++t) {
    const int ahead = nsteps - 1 - t;
    if (ahead >= DEPTH - 1)
      waitvm<(DEPTH - 1) * ISS>();
    else
      waitvm<0>();
    barrier_fence();
    compute(cur);
    if (t + 1 < nsteps) {
      asm volatile("s_waitcnt lgkmcnt(0)" ::: "memory");
      barrier_fence();
      if (t + DEPTH < nsteps) stage(cur, (t + DEPTH) * BK);
    }
    cur = (cur + 1 == DEPTH) ? 0 : cur + 1;
  }

#pragma unroll
  for (int m = 0; m < FM; ++m) {
    int gr0 = brow + wr * FM * 16 + m * 16 + fhi * 4;
#pragma unroll
    for (int n = 0; n < FN; ++n) {
      int gc = bcol + wc * FN * 16 + n * 16 + frow;
#pragma unroll
      for (int j = 0; j < 4; ++j) {
        size_t idx = (size_t)(gr0 + j) * N + gc;
        float v = acc[m][n][j];
        if constexpr (EPI == 2) {
          v += e0[gc];
          outf[idx] = v > 0.f ? v : 0.f;
        } else {
          outf[idx] = v;
        }
      }
    }
  }
}

// ====== f32-A GEMM core v2 (gemm01): 128x128, ALL-reg staging, 1 bar/step ====
// A (f32) and B (bf16) both loaded to REGISTERS (two named banks, static
// indexing), then written to the XOR-swizzled bf16 LDS layout.  Loads for
// tile t+2 issue at the START of step t => ~2 compute phases of latency
// cover; the compiler inserts exact counted vmcnt before bank reads.
// One lgkmcnt(0)+barrier per step.  nsteps must be EVEN (8 or 16 here).
// NON-TEMPLATE, single call site => single 64 KB LDS allocation.
__device__ __forceinline__ void gemm_core_f32a(
    const float* __restrict__ A, const unsigned short* __restrict__ Bt,
    int lda, int kchunk, float* __restrict__ outf, int nwg, int bid) {
  constexpr int N = 512;
  constexpr int BM = 128, BN = 128, BK = 64;
  __shared__ unsigned short lds[2][(BM + BN) * BK];  // 2 x 32 KB

  const int tid = threadIdx.x;
  const int wid = tid >> 6;
  const int lane = tid & 63;
  const int wr = wid >> 1, wc = wid & 1;

  const int swz = (bid & 7) * (nwg >> 3) + (bid >> 3);
  const int nbn = N / BN;        // 4
  const int brow = (swz / nbn) * BM;
  const int bcol = (swz % nbn) * BN;

  f32x4 zero = {0.f, 0.f, 0.f, 0.f};
  f32x4 acc[4][4];
#pragma unroll
  for (int m = 0; m < 4; ++m)
#pragma unroll
    for (int n = 0; n < 4; ++n) acc[m][n] = zero;

  const int lr = lane >> 3;      // 0..7
  const int lc = lane & 7;       // phys 16B chunk
  const int swzc = (lc ^ lr) * 8;
  const float* Agf = A + (size_t)(brow + wid * 32 + lr) * lda + swzc;
  const unsigned short* Bgh = Bt + (size_t)(bcol + wid * 32 + lr) * lda + swzc;

  const int frow = lane & 15;
  const int fhi = lane >> 4;

  const int nsteps = kchunk / BK;  // 16 or 8 (EVEN)

  float4 areg0[4][2], areg1[4][2];
  ushort8 breg0[4], breg1[4];

#define ALOAD(bank, kofs)                                              \
  _Pragma("unroll") for (int i = 0; i < 4; ++i) {                      \
    const float* s_ = Agf + (kofs) + (size_t)(8 * i) * lda;            \
    bank[i][0] = *reinterpret_cast<const float4*>(s_);                 \
    bank[i][1] = *reinterpret_cast<const float4*>(s_ + 4);             \
  }
#define BLOAD(bank, kofs)                                              \
  _Pragma("unroll") for (int i = 0; i < 4; ++i)                        \
    bank[i] = *reinterpret_cast<const ushort8*>(Bgh + (kofs) +         \
                                                (size_t)(8 * i) * lda);
#define AWRITE(buf, bank)                                              \
  {                                                                    \
    unsigned short* AsW_ = lds[buf] + wid * 2048 + lane * 8;           \
    _Pragma("unroll") for (int i = 0; i < 4; ++i) {                    \
      float4 x_ = bank[i][0], y_ = bank[i][1];                         \
      ushort8 o_;                                                      \
      o_[0] = f2bf(x_.x); o_[1] = f2bf(x_.y);                          \
      o_[2] = f2bf(x_.z); o_[3] = f2bf(x_.w);                          \
      o_[4] = f2bf(y_.x); o_[5] = f2bf(y_.y);                          \
      o_[6] = f2bf(y_.z); o_[7] = f2bf(y_.w);                          \
      *reinterpret_cast<ushort8*>(AsW_ + i * 512) = o_;                \
    }                                                                  \
  }
#define BWRITE(buf, bank)                                              \
  {                                                                    \
    unsigned short* BsW_ = lds[buf] + BM * BK + wid * 2048 + lane * 8; \
    _Pragma("unroll") for (int i = 0; i < 4; ++i)                      \
      *reinterpret_cast<ushort8*>(BsW_ + i * 512) = bank[i];           \
  }

  auto compute = [&](int cur) {
    const unsigned short* As = lds[cur];
    const unsigned short* Bs = lds[cur] + BM * BK;
#pragma unroll
    for (int ks = 0; ks < 2; ++ks) {
      bf16x8 af[4], bg[4];
#pragma unroll
      for (int m = 0; m < 4; ++m) {
        int row = wr * 64 + m * 16 + frow;
        int pc = (ks * 4 + fhi) ^ (row & 7);
        af[m] = *reinterpret_cast<const bf16x8*>(As + row * 64 + pc * 8);
      }
#pragma unroll
      for (int n = 0; n < 4; ++n) {
        int row = wc * 64 + n * 16 + frow;
        int pc = (ks * 4 + fhi) ^ (row & 7);
        bg[n] = *reinterpret_cast<const bf16x8*>(Bs + row * 64 + pc * 8);
      }
#pragma unroll
      for (int m = 0; m < 4; ++m)
#pragma unroll
        for (int n = 0; n < 4; ++n)
          acc[m][n] = __builtin_amdgcn_mfma_f32_16x16x32_bf16(af[m], bg[n],
                                                              acc[m][n], 0, 0, 0);
    }
  };

  // prologue: bank0 = tile0, bank1 = tile1 (in flight); buf0 <- tile0
  ALOAD(areg0, 0); BLOAD(breg0, 0);
  ALOAD(areg1, BK); BLOAD(breg1, BK);
  AWRITE(0, areg0); BWRITE(0, breg0);
  asm volatile("s_waitcnt lgkmcnt(0)" ::: "memory");
  barrier_fence();

  // main loop: 2 tiles per iteration, named banks (no dynamic reg indexing).
  // even tile t: compute buf0; write buf1 <- bank1 (tile t+1); bank0 <- t+2
  // odd tile t+1: compute buf1; write buf0 <- bank0 (t+2); bank1 <- t+3
  for (int t = 0; t < nsteps; t += 2) {
    if (t + 2 < nsteps) { ALOAD(areg0, (t + 2) * BK); BLOAD(breg0, (t + 2) * BK); }
    compute(0);
    AWRITE(1, areg1); BWRITE(1, breg1);   // tile t+1 (t+1 < nsteps: nsteps even)
    asm volatile("s_waitcnt lgkmcnt(0)" ::: "memory");
    barrier_fence();

    if (t + 3 < nsteps) { ALOAD(areg1, (t + 3) * BK); BLOAD(breg1, (t + 3) * BK); }
    compute(1);
    if (t + 2 < nsteps) {
      AWRITE(0, areg0); BWRITE(0, breg0); // tile t+2
      asm volatile("s_waitcnt lgkmcnt(0)" ::: "memory");
      barrier_fence();
    }
  }
#undef ALOAD
#undef BLOAD
#undef AWRITE
#undef BWRITE

  // epilogue: partial write
#pragma unroll
  for (int m = 0; m < 4; ++m) {
    int gr0 = brow + wr * 64 + m * 16 + fhi * 4;
#pragma unroll
    for (int n = 0; n < 4; ++n) {
      int gc = bcol + wc * 64 + n * 16 + frow;
#pragma unroll
      for (int j = 0; j < 4; ++j)
        outf[(size_t)(gr0 + j) * N + gc] = acc[m][n][j];
    }
  }
}

// ---- merged split-K partial GEMMs, all-reg staging, ONE call site ----
// blocks [0,256)   : inputs@U  split-4 (lda 4096, kchunk 1024) -> p1
// blocks [256,384) : context@W split-2 (lda 1024, kchunk  512) -> p0
__global__ __launch_bounds__(256) void gemm01_kernel(
    const float* __restrict__ inp, const unsigned short* __restrict__ Ut,
    const float* __restrict__ ctx, const unsigned short* __restrict__ Wt,
    float* __restrict__ p0, float* __restrict__ p1) {
  const int bid = (int)blockIdx.x;
  constexpr size_t MN = (size_t)2048 * 512;
  const float* A;
  const unsigned short* Bt;
  int lda, kchunk, lbid;
  float* outp;
  if (bid < 256) {
    const int split = bid >> 6;          // 4 splits x 64 positions
    A = inp + (size_t)split * 1024;
    Bt = Ut + (size_t)split * 1024;
    lda = 4096; kchunk = 1024; outp = p1 + split * MN; lbid = bid & 63;
  } else {
    const int sb = bid - 256;
    const int split = sb >> 6;           // 2 splits x 64 positions
    A = ctx + (size_t)split * 512;
    Bt = Wt + (size_t)split * 512;
    lda = 1024; kchunk = 512; outp = p0 + split * MN; lbid = sb & 63;
  }
  gemm_core_f32a(A, Bt, lda, kchunk, outp, 64, lbid);
}

// ---- final GEMM: out = relu(xus @ V^T + bias), 128x128, COLMAP ----
__global__ __launch_bounds__(256) void gemm2_kernel(
    const unsigned short* __restrict__ xus, const unsigned short* __restrict__ Vb,
    const float* __restrict__ bias, float* __restrict__ out) {
  gemm_core<4, 4, 2, 2, true>(xus, Vb, 4096, 512, 512, bias, out, 512,
                              (int)blockIdx.x);
}

// ---- fused split-K reduce: xus = bf16((sum p1) * (S + sum p0)) ----
__global__ void reduce_mul_kernel(const float* __restrict__ p1,  // [4][MN]
                                  const float* __restrict__ p0,  // [2][MN]
                                  const float* __restrict__ Svec,  // [512]
                                  unsigned short* __restrict__ xus, int MN) {
  int i = blockIdx.x * blockDim.x + threadIdx.x;
  size_t base = (size_t)i * 4;
  if (base >= (size_t)MN) return;
  float4 a = *reinterpret_cast<const float4*>(p1 + base);
  float4 b = *reinterpret_cast<const float4*>(p1 + (size_t)MN + base);
  float4 c = *reinterpret_cast<const float4*>(p1 + 2 * (size_t)MN + base);
  float4 d = *reinterpret_cast<const float4*>(p1 + 3 * (size_t)MN + base);
  float4 s0 = *reinterpret_cast<const float4*>(p0 + base);
  float4 s1 = *reinterpret_cast<const float4*>(p0 + (size_t)MN + base);
  float4 sv = *reinterpret_cast<const float4*>(Svec + (base & 511));
  float4 xu, s;
  xu.x = (a.x + b.x) + (c.x + d.x);  s.x = s0.x + s1.x + sv.x;
  xu.y = (a.y + b.y) + (c.y + d.y);  s.y = s0.y + s1.y + sv.y;
  xu.z = (a.z + b.z) + (c.z + d.z);  s.z = s0.z + s1.z + sv.z;
  xu.w = (a.w + b.w) + (c.w + d.w);  s.w = s0.w + s1.w + sv.w;
  ushort4v o;
  o[0] = f2bf(xu.x * s.x);
  o[1] = f2bf(xu.y * s.y);
  o[2] = f2bf(xu.z * s.z);
  o[3] = f2bf(xu.w * s.w);
  *reinterpret_cast<ushort4v*>(xus + base) = o;
}

extern "C" void kernel_launch(void* const* d_in, const int* in_sizes, int n_in,
                              void* d_out, int out_size, void* d_ws, size_t ws_size,
                              hipStream_t stream) {
  constexpr int Bm = 2048, Nn = 4096, Cc = 1024, UU = 4096, RR = 512;
  const float* inputs  = (const float*)d_in[0];
  const float* context = (const float*)d_in[1];
  const float* U       = (const float*)d_in[2];
  const float* S       = (const float*)d_in[3];
  const float* V       = (const float*)d_in[4];
  const float* W       = (const float*)d_in[5];
  const float* bias    = (const float*)d_in[6];
  float* out = (float*)d_out;

  char* p = (char*)d_ws;
  unsigned short* Ut   = (unsigned short*)p; p += (size_t)RR * Nn * 2;      //  4 MB
  unsigned short* Wt   = (unsigned short*)p; p += (size_t)RR * Cc * 2;      //  1 MB
  unsigned short* Vb   = (unsigned short*)p; p += (size_t)UU * RR * 2;      //  4 MB
  float*          p0   = (float*)p;          p += (size_t)2 * Bm * RR * 4;  //  8 MB
  float*          p1   = (float*)p;          p += (size_t)4 * Bm * RR * 4;  // 16 MB
  unsigned short* xus  = (unsigned short*)p; p += (size_t)Bm * RR * 2;      //  2 MB

  // 1) prep: U^T, W^T, V -> bf16
  prep_kernel<<<3584, 256, 0, stream>>>(U, Ut, W, Wt, V, Vb);

  // 2) merged split-K partials from f32 A (all-reg staging, 128x128)
  gemm01_kernel<<<384, 256, 0, stream>>>(inputs, Ut, context, Wt, p0, p1);

  // 3) xus = bf16((sum p1) * (S + sum p0))
  reduce_mul_kernel<<<Bm * RR / 4 / 256, 256, 0, stream>>>(p1, p0, S, xus, Bm * RR);

  // 4) out = relu(xus @ V^T + bias)   (128x128 tiles, col-chunked XCD map)
  gemm2_kernel<<<512, 256, 0, stream>>>(xus, Vb, bias, out);
}

// Round 18
// 58.040 us; speedup vs baseline: 1.1821x; 1.0416x over previous
//
#include <hip/hip_runtime.h>
#include <hip/hip_bf16.h>

typedef __attribute__((ext_vector_type(8))) __bf16 bf16x8;
typedef __attribute__((ext_vector_type(4))) float f32x4;
typedef __attribute__((ext_vector_type(8))) unsigned short ushort8;
typedef __attribute__((ext_vector_type(4))) unsigned short ushort4v;

__device__ __forceinline__ unsigned short f2bf(float f) {
  unsigned u = __builtin_bit_cast(unsigned, f);
  u += 0x7FFFu + ((u >> 16) & 1u);   // round-to-nearest-even
  return (unsigned short)(u >> 16);
}

__device__ __forceinline__ void gload_lds16(const void* g, void* l) {
  __builtin_amdgcn_global_load_lds(
      (const __attribute__((address_space(1))) void*)g,
      (__attribute__((address_space(3))) void*)l, 16, 0, 0);
}

__device__ __forceinline__ void barrier_fence() {
  __builtin_amdgcn_s_barrier();
  asm volatile("" ::: "memory");
}

template <int N>
__device__ __forceinline__ void waitvm() {
  if constexpr (N == 0)      asm volatile("s_waitcnt vmcnt(0)" ::: "memory");
  else if constexpr (N == 8) asm volatile("s_waitcnt vmcnt(8)" ::: "memory");
}

// ---- prep: all operand conversions in ONE launch (r6/r13 verbatim) ----
// [0,2048)    : U[4096][512] -> Ut[512][4096] bf16 (transpose)
// [2048,2560) : W[1024][512] -> Wt[512][1024] bf16 (transpose)
// [2560,3584) : V   (2M f32) -> Vb bf16
// [3584,7680) : inputs (8M)  -> inb bf16
// [7680,8704) : context (2M) -> ctxb bf16
__global__ __launch_bounds__(256) void prep_kernel(
    const float* __restrict__ U, unsigned short* __restrict__ Ut,
    const float* __restrict__ W, unsigned short* __restrict__ Wt,
    const float* __restrict__ V, unsigned short* __restrict__ Vb,
    const float* __restrict__ inp, unsigned short* __restrict__ inb,
    const float* __restrict__ ctx, unsigned short* __restrict__ ctxb) {
  __shared__ float tile[32][33];
  const int b = blockIdx.x;
  const int tid = threadIdx.x;
  if (b < 2560) {
    const float* src;
    unsigned short* dst;
    int rows, cols, bx, by;
    if (b < 2048) {
      src = U; dst = Ut; rows = 4096; cols = 512;
      bx = (b & 15) * 32; by = (b >> 4) * 32;
    } else {
      int bb = b - 2048;
      src = W; dst = Wt; rows = 1024; cols = 512;
      bx = (bb & 15) * 32; by = (bb >> 4) * 32;
    }
    const int tx = tid & 31, ty = tid >> 5;
    for (int i = ty; i < 32; i += 8)
      tile[i][tx] = src[(size_t)(by + i) * cols + bx + tx];
    __syncthreads();
    for (int i = ty; i < 32; i += 8)
      dst[(size_t)(bx + i) * rows + by + tx] = f2bf(tile[tx][i]);
  } else {
    const float* src;
    unsigned short* dst;
    size_t i;
    if (b < 3584)      { src = V;   dst = Vb;   i = (size_t)(b - 2560) * 256 + tid; }
    else if (b < 7680) { src = inp; dst = inb;  i = (size_t)(b - 3584) * 256 + tid; }
    else               { src = ctx; dst = ctxb; i = (size_t)(b - 7680) * 256 + tid; }
    const float4* s4 = reinterpret_cast<const float4*>(src) + 2 * i;
    float4 a = s4[0], c = s4[1];
    ushort8 o;
    o[0] = f2bf(a.x); o[1] = f2bf(a.y); o[2] = f2bf(a.z); o[3] = f2bf(a.w);
    o[4] = f2bf(c.x); o[5] = f2bf(c.y); o[6] = f2bf(c.z); o[7] = f2bf(c.w);
    *(reinterpret_cast<ushort8*>(dst) + i) = o;
  }
}

// -------- bf16 GEMM core: 128x128 tile, BK=64, counted-vmcnt DEPTH=2 --------
// r13-proven.  A,Bt bf16 via global_load_lds; caller passes both already
// offset to the K-chunk start.  COLMAP: XCD chunks advance along rows within
// a column stripe (B-panel L2 reuse, for gemm2's 4K-wide output).
// EPI 2: outf[idx] = relu(acc + e0[col]); EPI 3: outf[idx] = acc (partial).
template <int FM, int FN, int EPI, int DEPTH, bool COLMAP>
__device__ __forceinline__ void gemm_core(
    const unsigned short* __restrict__ A, const unsigned short* __restrict__ Bt,
    int N, int lda, int kchunk, const float* __restrict__ e0,
    float* __restrict__ outf, int nwg, int bid) {
  constexpr int BM = 32 * FM, BN = 32 * FN, BK = 64;
  constexpr int AI = FM, BI = FN;
  constexpr int ISS = AI + BI;
  __shared__ unsigned short lds[DEPTH][(BM + BN) * BK];

  const int tid = threadIdx.x;
  const int wid = tid >> 6;
  const int lane = tid & 63;
  const int wr = wid >> 1, wc = wid & 1;

  const int swz = (bid & 7) * (nwg >> 3) + (bid >> 3);
  const int nbn = N / BN;
  int brow, bcol;
  if constexpr (COLMAP) {
    const int nbm = nwg / nbn;
    brow = (swz % nbm) * BM;
    bcol = (swz / nbm) * BN;
  } else {
    brow = (swz / nbn) * BM;
    bcol = (swz % nbn) * BN;
  }

  f32x4 zero = {0.f, 0.f, 0.f, 0.f};
  f32x4 acc[FM][FN];
#pragma unroll
  for (int m = 0; m < FM; ++m)
#pragma unroll
    for (int n = 0; n < FN; ++n) acc[m][n] = zero;

  const int lr = lane >> 3;
  const int swzc = ((lane & 7) ^ lr) * 8;     // pre-swizzled source col (elems)
  const unsigned short* Agh = A + (size_t)(brow + wid * (BM / 4) + lr) * lda + swzc;
  const unsigned short* Bgh = Bt + (size_t)(bcol + wid * (BN / 4) + lr) * lda + swzc;

  const int frow = lane & 15;
  const int fhi = lane >> 4;

  const int nsteps = kchunk / BK;

  auto stage = [&](int b, int kofs) {   // kofs in ELEMENTS (t*BK)
    unsigned short* AsW = lds[b] + wid * (BM / 4) * 64;
#pragma unroll
    for (int i = 0; i < AI; ++i)
      gload_lds16(Agh + kofs + (size_t)(8 * i) * lda, AsW + i * 512);
    unsigned short* BsW = lds[b] + BM * BK + wid * (BN / 4) * 64;
#pragma unroll
    for (int i = 0; i < BI; ++i)
      gload_lds16(Bgh + kofs + (size_t)(8 * i) * lda, BsW + i * 512);
  };

  auto compute = [&](int cur) {
    const unsigned short* As = lds[cur];
    const unsigned short* Bs = lds[cur] + BM * BK;
#pragma unroll
    for (int ks = 0; ks < 2; ++ks) {
      bf16x8 af[FM], bg[FN];
#pragma unroll
      for (int m = 0; m < FM; ++m) {
        int row = wr * FM * 16 + m * 16 + frow;
        int pc = (ks * 4 + fhi) ^ (row & 7);
        af[m] = *reinterpret_cast<const bf16x8*>(As + row * 64 + pc * 8);
      }
#pragma unroll
      for (int n = 0; n < FN; ++n) {
        int row = wc * FN * 16 + n * 16 + frow;
        int pc = (ks * 4 + fhi) ^ (row & 7);
        bg[n] = *reinterpret_cast<const bf16x8*>(Bs + row * 64 + pc * 8);
      }
#pragma unroll
      for (int m = 0; m < FM; ++m)
#pragma unroll
        for (int n = 0; n < FN; ++n)
          acc[m][n] = __builtin_amdgcn_mfma_f32_16x16x32_bf16(af[m], bg[n],
                                                              acc[m][n], 0, 0, 0);
    }
  };

#pragma unroll
  for (int d = 0; d < DEPTH; ++d) stage(d, d * BK);

  int cur = 0;
  for (int t = 0; t < nsteps; ++t) {
    const int ahead = nsteps - 1 - t;
    if (ahead >= DEPTH - 1)
      waitvm<(DEPTH - 1) * ISS>();
    else
      waitvm<0>();
    barrier_fence();
    compute(cur);
    if (t + 1 < nsteps) {
      asm volatile("s_waitcnt lgkmcnt(0)" ::: "memory");
      barrier_fence();
      if (t + DEPTH < nsteps) stage(cur, (t + DEPTH) * BK);
    }
    cur = (cur + 1 == DEPTH) ? 0 : cur + 1;
  }

  // epilogue: D col = lane&15, row = (lane>>4)*4 + j
#pragma unroll
  for (int m = 0; m < FM; ++m) {
    int gr0 = brow + wr * FM * 16 + m * 16 + fhi * 4;
#pragma unroll
    for (int n = 0; n < FN; ++n) {
      int gc = bcol + wc * FN * 16 + n * 16 + frow;
#pragma unroll
      for (int j = 0; j < 4; ++j) {
        size_t idx = (size_t)(gr0 + j) * N + gc;
        float v = acc[m][n][j];
        if constexpr (EPI == 2) {
          v += e0[gc];
          outf[idx] = v > 0.f ? v : 0.f;
        } else {
          outf[idx] = v;
        }
      }
    }
  }
}

// ---- merged split-K partial GEMMs, all-bf16, UNIFORM 8-step blocks ----
// blocks [0,512)   : inputs@U  split-8 (lda 4096, kchunk 512) -> p1[8]
// blocks [512,640) : context@W split-2 (lda 1024, kchunk 512) -> p0[2]
// K-chunk offset applied to BOTH A and Bt.  One instantiation/call site.
__global__ __launch_bounds__(256) void gemm01_kernel(
    const unsigned short* __restrict__ inb, const unsigned short* __restrict__ Ut,
    const unsigned short* __restrict__ ctxb, const unsigned short* __restrict__ Wt,
    float* __restrict__ p0, float* __restrict__ p1) {
  const int bid = (int)blockIdx.x;
  constexpr size_t MN = (size_t)2048 * 512;
  const unsigned short *A, *Bt;
  int lda, lbid;
  float* outp;
  if (bid < 512) {
    const int split = bid >> 6;          // 8 splits x 64 positions
    A = inb + (size_t)split * 512;
    Bt = Ut + (size_t)split * 512;
    lda = 4096; outp = p1 + split * MN; lbid = bid & 63;
  } else {
    const int sb = bid - 512;
    const int split = sb >> 6;           // 2 splits x 64 positions
    A = ctxb + (size_t)split * 512;
    Bt = Wt + (size_t)split * 512;
    lda = 1024; outp = p0 + split * MN; lbid = sb & 63;
  }
  gemm_core<4, 4, 3, 2, false>(A, Bt, 512, lda, 512, nullptr, outp, 64, lbid);
}

// ---- final GEMM: out = relu(xus @ V^T + bias), 128x128, COLMAP ----
__global__ __launch_bounds__(256) void gemm2_kernel(
    const unsigned short* __restrict__ xus, const unsigned short* __restrict__ Vb,
    const float* __restrict__ bias, float* __restrict__ out) {
  gemm_core<4, 4, 2, 2, true>(xus, Vb, 4096, 512, 512, bias, out, 512,
                              (int)blockIdx.x);
}

// ---- fused split-K reduce: xus = bf16((sum p1[0..8)) * (S + p0[0] + p0[1])) --
__global__ void reduce_mul_kernel(const float* __restrict__ p1,  // [8][MN]
                                  const float* __restrict__ p0,  // [2][MN]
                                  const float* __restrict__ Svec,  // [512]
                                  unsigned short* __restrict__ xus, int MN) {
  int i = blockIdx.x * blockDim.x + threadIdx.x;
  size_t base = (size_t)i * 4;
  if (base >= (size_t)MN) return;
  float4 xu = {0.f, 0.f, 0.f, 0.f};
#pragma unroll
  for (int k = 0; k < 8; ++k) {
    float4 a = *reinterpret_cast<const float4*>(p1 + (size_t)k * MN + base);
    xu.x += a.x; xu.y += a.y; xu.z += a.z; xu.w += a.w;
  }
  float4 s0 = *reinterpret_cast<const float4*>(p0 + base);
  float4 s1 = *reinterpret_cast<const float4*>(p0 + (size_t)MN + base);
  float4 sv = *reinterpret_cast<const float4*>(Svec + (base & 511));
  float4 s;
  s.x = s0.x + s1.x + sv.x;
  s.y = s0.y + s1.y + sv.y;
  s.z = s0.z + s1.z + sv.z;
  s.w = s0.w + s1.w + sv.w;
  ushort4v o;
  o[0] = f2bf(xu.x * s.x);
  o[1] = f2bf(xu.y * s.y);
  o[2] = f2bf(xu.z * s.z);
  o[3] = f2bf(xu.w * s.w);
  *reinterpret_cast<ushort4v*>(xus + base) = o;
}

extern "C" void kernel_launch(void* const* d_in, const int* in_sizes, int n_in,
                              void* d_out, int out_size, void* d_ws, size_t ws_size,
                              hipStream_t stream) {
  constexpr int Bm = 2048, Nn = 4096, Cc = 1024, UU = 4096, RR = 512;
  const float* inputs  = (const float*)d_in[0];
  const float* context = (const float*)d_in[1];
  const float* U       = (const float*)d_in[2];
  const float* S       = (const float*)d_in[3];
  const float* V       = (const float*)d_in[4];
  const float* W       = (const float*)d_in[5];
  const float* bias    = (const float*)d_in[6];
  float* out = (float*)d_out;

  char* p = (char*)d_ws;
  unsigned short* Ut   = (unsigned short*)p; p += (size_t)RR * Nn * 2;      //  4 MB
  unsigned short* Wt   = (unsigned short*)p; p += (size_t)RR * Cc * 2;      //  1 MB
  unsigned short* Vb   = (unsigned short*)p; p += (size_t)UU * RR * 2;      //  4 MB
  unsigned short* inb  = (unsigned short*)p; p += (size_t)Bm * Nn * 2;      // 16 MB
  unsigned short* ctxb = (unsigned short*)p; p += (size_t)Bm * Cc * 2;      //  4 MB
  float*          p0   = (float*)p;          p += (size_t)2 * Bm * RR * 4;  //  8 MB
  float*          p1   = (float*)p;          p += (size_t)8 * Bm * RR * 4;  // 32 MB
  unsigned short* xus  = (unsigned short*)p; p += (size_t)Bm * RR * 2;      //  2 MB

  // 1) prep: all conversions (U^T, W^T, V, inputs, context -> bf16)
  prep_kernel<<<8704, 256, 0, stream>>>(U, Ut, W, Wt, V, Vb, inputs, inb,
                                        context, ctxb);

  // 2) merged split-K partials: p1[8] = inputs@U, p0[2] = context@W
  //    (all blocks uniform: 128x128 tile, 8 K-steps)
  gemm01_kernel<<<640, 256, 0, stream>>>(inb, Ut, ctxb, Wt, p0, p1);

  // 3) xus = bf16((sum p1) * (S + sum p0))
  reduce_mul_kernel<<<Bm * RR / 4 / 256, 256, 0, stream>>>(p1, p0, S, xus, Bm * RR);

  // 4) out = relu(xus @ V^T + bias)   (128x128 tiles, col-chunked XCD map)
  gemm2_kernel<<<512, 256, 0, stream>>>(xus, Vb, bias, out);
}

// Round 19
// 50.561 us; speedup vs baseline: 1.3569x; 1.1479x over previous
//
#include <hip/hip_runtime.h>
#include <hip/hip_bf16.h>

typedef __attribute__((ext_vector_type(8))) __bf16 bf16x8;
typedef __attribute__((ext_vector_type(4))) float f32x4;
typedef __attribute__((ext_vector_type(8))) unsigned short ushort8;

__device__ __forceinline__ unsigned short f2bf(float f) {
  unsigned u = __builtin_bit_cast(unsigned, f);
  u += 0x7FFFu + ((u >> 16) & 1u);   // round-to-nearest-even
  return (unsigned short)(u >> 16);
}

__device__ __forceinline__ float bf2f(unsigned short h) {
  return __builtin_bit_cast(float, (unsigned)h << 16);
}

__device__ __forceinline__ void gload_lds16(const void* g, void* l) {
  __builtin_amdgcn_global_load_lds(
      (const __attribute__((address_space(1))) void*)g,
      (__attribute__((address_space(3))) void*)l, 16, 0, 0);
}

__device__ __forceinline__ void barrier_fence() {
  __builtin_amdgcn_s_barrier();
  asm volatile("" ::: "memory");
}

template <int N>
__device__ __forceinline__ void waitvm() {
  if constexpr (N == 0)      asm volatile("s_waitcnt vmcnt(0)" ::: "memory");
  else if constexpr (N == 8) asm volatile("s_waitcnt vmcnt(8)" ::: "memory");
}

// ---- prep: weight conversions only (r14 verbatim) ----
// [0,2048)    : U[4096][512] -> Ut[512][4096] bf16 (transpose)
// [2048,2560) : W[1024][512] -> Wt[512][1024] bf16 (transpose)
// [2560,3584) : V   (2M f32) -> Vb bf16
__global__ __launch_bounds__(256) void prep_kernel(
    const float* __restrict__ U, unsigned short* __restrict__ Ut,
    const float* __restrict__ W, unsigned short* __restrict__ Wt,
    const float* __restrict__ V, unsigned short* __restrict__ Vb) {
  __shared__ float tile[32][33];
  const int b = blockIdx.x;
  const int tid = threadIdx.x;
  if (b < 2560) {
    const float* src;
    unsigned short* dst;
    int rows, cols, bx, by;
    if (b < 2048) {
      src = U; dst = Ut; rows = 4096; cols = 512;
      bx = (b & 15) * 32; by = (b >> 4) * 32;
    } else {
      int bb = b - 2048;
      src = W; dst = Wt; rows = 1024; cols = 512;
      bx = (bb & 15) * 32; by = (bb >> 4) * 32;
    }
    const int tx = tid & 31, ty = tid >> 5;
    for (int i = ty; i < 32; i += 8)
      tile[i][tx] = src[(size_t)(by + i) * cols + bx + tx];
    __syncthreads();
    for (int i = ty; i < 32; i += 8)
      dst[(size_t)(bx + i) * rows + by + tx] = f2bf(tile[tx][i]);
  } else {
    const size_t i = (size_t)(b - 2560) * 256 + tid;  // 8 f32 per thread
    const float4* s4 = reinterpret_cast<const float4*>(V) + 2 * i;
    float4 a = s4[0], c = s4[1];
    ushort8 o;
    o[0] = f2bf(a.x); o[1] = f2bf(a.y); o[2] = f2bf(a.z); o[3] = f2bf(a.w);
    o[4] = f2bf(c.x); o[5] = f2bf(c.y); o[6] = f2bf(c.z); o[7] = f2bf(c.w);
    *(reinterpret_cast<ushort8*>(Vb) + i) = o;
  }
}

// ======== bf16 GEMM core (gemm2): 128x128, counted-vmcnt DEPTH=2 ========
// A,Bt bf16 via global_load_lds.  COLMAP: XCD chunks advance along rows
// within a column stripe (each XCD touches 4 of 32 B-panels -> L2-local B).
// EPI 2: outf[idx] = relu(acc + e0[col]).
template <int FM, int FN, int EPI, int DEPTH, bool COLMAP>
__device__ __forceinline__ void gemm_core(
    const unsigned short* __restrict__ A, const unsigned short* __restrict__ Bt,
    int N, int lda, int kchunk, const float* __restrict__ e0,
    float* __restrict__ outf, int nwg, int bid) {
  constexpr int BM = 32 * FM, BN = 32 * FN, BK = 64;
  constexpr int AI = FM, BI = FN;
  constexpr int ISS = AI + BI;
  __shared__ unsigned short lds[DEPTH][(BM + BN) * BK];

  const int tid = threadIdx.x;
  const int wid = tid >> 6;
  const int lane = tid & 63;
  const int wr = wid >> 1, wc = wid & 1;

  const int swz = (bid & 7) * (nwg >> 3) + (bid >> 3);
  const int nbn = N / BN;
  int brow, bcol;
  if constexpr (COLMAP) {
    const int nbm = nwg / nbn;
    brow = (swz % nbm) * BM;
    bcol = (swz / nbm) * BN;
  } else {
    brow = (swz / nbn) * BM;
    bcol = (swz % nbn) * BN;
  }

  f32x4 zero = {0.f, 0.f, 0.f, 0.f};
  f32x4 acc[FM][FN];
#pragma unroll
  for (int m = 0; m < FM; ++m)
#pragma unroll
    for (int n = 0; n < FN; ++n) acc[m][n] = zero;

  const int lr = lane >> 3;
  const int swzc = ((lane & 7) ^ lr) * 8;
  const unsigned short* Agh = A + (size_t)(brow + wid * (BM / 4) + lr) * lda + swzc;
  const unsigned short* Bgh = Bt + (size_t)(bcol + wid * (BN / 4) + lr) * lda + swzc;

  const int frow = lane & 15;
  const int fhi = lane >> 4;

  const int nsteps = kchunk / BK;

  auto stage = [&](int b, int kofs) {
    unsigned short* AsW = lds[b] + wid * (BM / 4) * 64;
#pragma unroll
    for (int i = 0; i < AI; ++i)
      gload_lds16(Agh + kofs + (size_t)(8 * i) * lda, AsW + i * 512);
    unsigned short* BsW = lds[b] + BM * BK + wid * (BN / 4) * 64;
#pragma unroll
    for (int i = 0; i < BI; ++i)
      gload_lds16(Bgh + kofs + (size_t)(8 * i) * lda, BsW + i * 512);
  };

  auto compute = [&](int cur) {
    const unsigned short* As = lds[cur];
    const unsigned short* Bs = lds[cur] + BM * BK;
#pragma unroll
    for (int ks = 0; ks < 2; ++ks) {
      bf16x8 af[FM], bg[FN];
#pragma unroll
      for (int m = 0; m < FM; ++m) {
        int row = wr * FM * 16 + m * 16 + frow;
        int pc = (ks * 4 + fhi) ^ (row & 7);
        af[m] = *reinterpret_cast<const bf16x8*>(As + row * 64 + pc * 8);
      }
#pragma unroll
      for (int n = 0; n < FN; ++n) {
        int row = wc * FN * 16 + n * 16 + frow;
        int pc = (ks * 4 + fhi) ^ (row & 7);
        bg[n] = *reinterpret_cast<const bf16x8*>(Bs + row * 64 + pc * 8);
      }
#pragma unroll
      for (int m = 0; m < FM; ++m)
#pragma unroll
        for (int n = 0; n < FN; ++n)
          acc[m][n] = __builtin_amdgcn_mfma_f32_16x16x32_bf16(af[m], bg[n],
                                                              acc[m][n], 0, 0, 0);
    }
  };

#pragma unroll
  for (int d = 0; d < DEPTH; ++d) stage(d, d * BK);

  int cur = 0;
  for (int t = 0; t < nsteps; ++t) {
    const int ahead = nsteps - 1 - t;
    if (ahead >= DEPTH - 1)
      waitvm<(DEPTH - 1) * ISS>();
    else
      waitvm<0>();
    barrier_fence();
    compute(cur);
    if (t + 1 < nsteps) {
      asm volatile("s_waitcnt lgkmcnt(0)" ::: "memory");
      barrier_fence();
      if (t + DEPTH < nsteps) stage(cur, (t + DEPTH) * BK);
    }
    cur = (cur + 1 == DEPTH) ? 0 : cur + 1;
  }

#pragma unroll
  for (int m = 0; m < FM; ++m) {
    int gr0 = brow + wr * FM * 16 + m * 16 + fhi * 4;
#pragma unroll
    for (int n = 0; n < FN; ++n) {
      int gc = bcol + wc * FN * 16 + n * 16 + frow;
#pragma unroll
      for (int j = 0; j < 4; ++j) {
        size_t idx = (size_t)(gr0 + j) * N + gc;
        float v = acc[m][n][j];
        if constexpr (EPI == 2) {
          v += e0[gc];
          outf[idx] = v > 0.f ? v : 0.f;
        } else {
          outf[idx] = v;
        }
      }
    }
  }
}

// ======== f32-A GEMM core (gemm01): r14 schedule verbatim, bf16 partials ====
// A f32 -> regs -> f2bf -> ds_write (fused cvt); B bf16 via global_load_lds.
// Step t: bload(t+1) | compute(t) | vmcnt(0) | awrite(t+1) | aload(t+2) |
// lgkm(0) | barrier.  NON-TEMPLATE, single call site (one 64 KB LDS alloc).
// Epilogue: outb[idx] = bf16(acc)  (split-K partial in bf16).
__device__ __forceinline__ void gemm_core_f32a(
    const float* __restrict__ A, const unsigned short* __restrict__ Bt,
    int lda, int kchunk, unsigned short* __restrict__ outb, int nwg, int bid) {
  constexpr int N = 512;
  constexpr int BM = 128, BN = 128, BK = 64;
  __shared__ unsigned short lds[2][(BM + BN) * BK];  // 2 x 32 KB

  const int tid = threadIdx.x;
  const int wid = tid >> 6;
  const int lane = tid & 63;
  const int wr = wid >> 1, wc = wid & 1;

  const int swz = (bid & 7) * (nwg >> 3) + (bid >> 3);
  const int nbn = N / BN;        // 4
  const int brow = (swz / nbn) * BM;
  const int bcol = (swz % nbn) * BN;

  f32x4 zero = {0.f, 0.f, 0.f, 0.f};
  f32x4 acc[4][4];
#pragma unroll
  for (int m = 0; m < 4; ++m)
#pragma unroll
    for (int n = 0; n < 4; ++n) acc[m][n] = zero;

  const int lr = lane >> 3;      // 0..7
  const int lc = lane & 7;       // phys 16B chunk
  const int swzc = (lc ^ lr) * 8;
  const float* Agf = A + (size_t)(brow + wid * 32 + lr) * lda + swzc;
  const unsigned short* Bgh = Bt + (size_t)(bcol + wid * 32 + lr) * lda + swzc;

  const int frow = lane & 15;
  const int fhi = lane >> 4;

  const int nsteps = kchunk / BK;  // 16 or 8

  float4 areg[4][2];
  auto aload = [&](int kofs) {
#pragma unroll
    for (int i = 0; i < 4; ++i) {
      const float* s = Agf + kofs + (size_t)(8 * i) * lda;
      areg[i][0] = *reinterpret_cast<const float4*>(s);
      areg[i][1] = *reinterpret_cast<const float4*>(s + 4);
    }
  };
  auto awrite = [&](int b) {
    unsigned short* AsW = lds[b] + wid * 2048 + lane * 8;
#pragma unroll
    for (int i = 0; i < 4; ++i) {
      float4 x = areg[i][0], y = areg[i][1];
      ushort8 o;
      o[0] = f2bf(x.x); o[1] = f2bf(x.y); o[2] = f2bf(x.z); o[3] = f2bf(x.w);
      o[4] = f2bf(y.x); o[5] = f2bf(y.y); o[6] = f2bf(y.z); o[7] = f2bf(y.w);
      *reinterpret_cast<ushort8*>(AsW + i * 512) = o;
    }
  };
  auto bload = [&](int b, int kofs) {
    unsigned short* BsW = lds[b] + BM * BK + wid * 2048;
#pragma unroll
    for (int i = 0; i < 4; ++i)
      gload_lds16(Bgh + kofs + (size_t)(8 * i) * lda, BsW + i * 512);
  };

  auto compute = [&](int cur) {
    const unsigned short* As = lds[cur];
    const unsigned short* Bs = lds[cur] + BM * BK;
#pragma unroll
    for (int ks = 0; ks < 2; ++ks) {
      bf16x8 af[4], bg[4];
#pragma unroll
      for (int m = 0; m < 4; ++m) {
        int row = wr * 64 + m * 16 + frow;
        int pc = (ks * 4 + fhi) ^ (row & 7);
        af[m] = *reinterpret_cast<const bf16x8*>(As + row * 64 + pc * 8);
      }
#pragma unroll
      for (int n = 0; n < 4; ++n) {
        int row = wc * 64 + n * 16 + frow;
        int pc = (ks * 4 + fhi) ^ (row & 7);
        bg[n] = *reinterpret_cast<const bf16x8*>(Bs + row * 64 + pc * 8);
      }
#pragma unroll
      for (int m = 0; m < 4; ++m)
#pragma unroll
        for (int n = 0; n < 4; ++n)
          acc[m][n] = __builtin_amdgcn_mfma_f32_16x16x32_bf16(af[m], bg[n],
                                                              acc[m][n], 0, 0, 0);
    }
  };

  // prologue: A(0)+B(0) staged & written; A(1) in flight to regs
  aload(0);
  bload(0, 0);
  waitvm<0>();
  awrite(0);
  aload(BK);
  asm volatile("s_waitcnt lgkmcnt(0)" ::: "memory");
  barrier_fence();

  for (int t = 0; t < nsteps; ++t) {
    const int cur = t & 1;
    if (t + 1 < nsteps) bload(cur ^ 1, (t + 1) * BK);
    compute(cur);
    if (t + 1 < nsteps) {
      waitvm<0>();     // my A(t+1) regs + my B(t+1) portion landed
      awrite(cur ^ 1);
      if (t + 2 < nsteps) aload((t + 2) * BK);
      asm volatile("s_waitcnt lgkmcnt(0)" ::: "memory");
      barrier_fence();
    }
  }

  // epilogue: bf16 partial write
#pragma unroll
  for (int m = 0; m < 4; ++m) {
    int gr0 = brow + wr * 64 + m * 16 + fhi * 4;
#pragma unroll
    for (int n = 0; n < 4; ++n) {
      int gc = bcol + wc * 64 + n * 16 + frow;
#pragma unroll
      for (int j = 0; j < 4; ++j)
        outb[(size_t)(gr0 + j) * N + gc] = f2bf(acc[m][n][j]);
    }
  }
}

// ---- merged split-K partial GEMMs, ONE call site (LDS lesson, r15) ----
// blocks [0,256)   : inputs@U  split-4 (lda 4096, kchunk 1024) -> p1b[4]
// blocks [256,384) : context@W split-2 (lda 1024, kchunk  512) -> p0b[2]
__global__ __launch_bounds__(256) void gemm01_kernel(
    const float* __restrict__ inp, const unsigned short* __restrict__ Ut,
    const float* __restrict__ ctx, const unsigned short* __restrict__ Wt,
    unsigned short* __restrict__ p0b, unsigned short* __restrict__ p1b) {
  const int bid = (int)blockIdx.x;
  constexpr size_t MN = (size_t)2048 * 512;
  const float* A;
  const unsigned short* Bt;
  int lda, kchunk, lbid;
  unsigned short* outp;
  if (bid < 256) {
    const int split = bid >> 6;          // 4 splits x 64 positions
    A = inp + (size_t)split * 1024;
    Bt = Ut + (size_t)split * 1024;
    lda = 4096; kchunk = 1024; outp = p1b + split * MN; lbid = bid & 63;
  } else {
    const int sb = bid - 256;
    const int split = sb >> 6;           // 2 splits x 64 positions
    A = ctx + (size_t)split * 512;
    Bt = Wt + (size_t)split * 512;
    lda = 1024; kchunk = 512; outp = p0b + split * MN; lbid = sb & 63;
  }
  gemm_core_f32a(A, Bt, lda, kchunk, outp, 64, lbid);
}

// ---- final GEMM: out = relu(xus @ V^T + bias), 128x128, COLMAP ----
__global__ __launch_bounds__(256) void gemm2_kernel(
    const unsigned short* __restrict__ xus, const unsigned short* __restrict__ Vb,
    const float* __restrict__ bias, float* __restrict__ out) {
  gemm_core<4, 4, 2, 2, true>(xus, Vb, 4096, 512, 512, bias, out, 512,
                              (int)blockIdx.x);
}

// ---- fused split-K reduce (bf16 partials): xus = bf16((sum p1) * (S + sum p0))
__global__ void reduce_mul_kernel(const unsigned short* __restrict__ p1,  // [4][MN]
                                  const unsigned short* __restrict__ p0,  // [2][MN]
                                  const float* __restrict__ Svec,         // [512]
                                  unsigned short* __restrict__ xus, int MN) {
  int i = blockIdx.x * blockDim.x + threadIdx.x;
  size_t base = (size_t)i * 8;
  if (base >= (size_t)MN) return;
  float xu[8] = {0.f, 0.f, 0.f, 0.f, 0.f, 0.f, 0.f, 0.f};
#pragma unroll
  for (int k = 0; k < 4; ++k) {
    ushort8 a = *reinterpret_cast<const ushort8*>(p1 + (size_t)k * MN + base);
#pragma unroll
    for (int j = 0; j < 8; ++j) xu[j] += bf2f(a[j]);
  }
  ushort8 s0 = *reinterpret_cast<const ushort8*>(p0 + base);
  ushort8 s1 = *reinterpret_cast<const ushort8*>(p0 + (size_t)MN + base);
  const float* sv = Svec + (base & 511);   // base%8==0, no wrap within 8
  ushort8 o;
#pragma unroll
  for (int j = 0; j < 8; ++j) {
    float s = bf2f(s0[j]) + bf2f(s1[j]) + sv[j];
    o[j] = f2bf(xu[j] * s);
  }
  *reinterpret_cast<ushort8*>(xus + base) = o;
}

extern "C" void kernel_launch(void* const* d_in, const int* in_sizes, int n_in,
                              void* d_out, int out_size, void* d_ws, size_t ws_size,
                              hipStream_t stream) {
  constexpr int Bm = 2048, Nn = 4096, Cc = 1024, UU = 4096, RR = 512;
  const float* inputs  = (const float*)d_in[0];
  const float* context = (const float*)d_in[1];
  const float* U       = (const float*)d_in[2];
  const float* S       = (const float*)d_in[3];
  const float* V       = (const float*)d_in[4];
  const float* W       = (const float*)d_in[5];
  const float* bias    = (const float*)d_in[6];
  float* out = (float*)d_out;

  char* p = (char*)d_ws;
  unsigned short* Ut   = (unsigned short*)p; p += (size_t)RR * Nn * 2;      //  4 MB
  unsigned short* Wt   = (unsigned short*)p; p += (size_t)RR * Cc * 2;      //  1 MB
  unsigned short* Vb   = (unsigned short*)p; p += (size_t)UU * RR * 2;      //  4 MB
  unsigned short* p0b  = (unsigned short*)p; p += (size_t)2 * Bm * RR * 2;  //  4 MB
  unsigned short* p1b  = (unsigned short*)p; p += (size_t)4 * Bm * RR * 2;  //  8 MB
  unsigned short* xus  = (unsigned short*)p; p += (size_t)Bm * RR * 2;      //  2 MB

  // 1) prep: U^T, W^T, V -> bf16 (inputs/context conversion fused into gemm01)
  prep_kernel<<<3584, 256, 0, stream>>>(U, Ut, W, Wt, V, Vb);

  // 2) merged split-K partials from f32 A (128x128 tiles, fused cvt, bf16 out)
  gemm01_kernel<<<384, 256, 0, stream>>>(inputs, Ut, context, Wt, p0b, p1b);

  // 3) xus = bf16((sum p1) * (S + sum p0))   (bf16 partials)
  reduce_mul_kernel<<<Bm * RR / 8 / 256, 256, 0, stream>>>(p1b, p0b, S, xus, Bm * RR);

  // 4) out = relu(xus @ V^T + bias)   (128x128 tiles, col-chunked XCD map)
  gemm2_kernel<<<512, 256, 0, stream>>>(xus, Vb, bias, out);
}